// Round 5
// baseline (367.921 us; speedup 1.0000x reference)
//
#include <hip/hip_runtime.h>

#define NN 100000
#define EE 600000
#define GG 1000
#define CAP 32          // bucket slots/node: up to 30 edges + self + pads (deg max ~25)
#define LDSPAD 136
#define INITB ((GG * 128 + 255) / 256)   // covers sums(128K), cnt(100K), gstart(1001)

typedef __bf16 bf16x8 __attribute__((ext_vector_type(8)));
typedef float f32x4 __attribute__((ext_vector_type(4)));
typedef unsigned int u32;

__device__ inline float2 bf2_to_f2(u32 u) {
  return make_float2(__uint_as_float(u << 16), __uint_as_float(u & 0xffff0000u));
}
__device__ inline u32 f2_to_bf2(float a, float b) {
  union { __bf16 h[2]; u32 u; } pk;
  pk.h[0] = (__bf16)a; pk.h[1] = (__bf16)b;
  return pk.u;
}

// ---------------- setup ----------------

__global__ void k_init(int* cnt, int* gstart, float* sums) {
  int i = blockIdx.x * 256 + threadIdx.x;
  if (i < NN) cnt[i] = 0;
  if (i <= GG) gstart[i] = NN;
  if (i < GG * 128) sums[i] = 0.f;
}

// writes src ids directly into wbucket.x (no separate ibucket buffer)
__global__ void k_fill(const int* __restrict__ src, const int* __restrict__ dst,
                       int* cnt, int2* __restrict__ wbucket) {
  int e = blockIdx.x * 256 + threadIdx.x;
  if (e >= EE) return;
  int s = src[e], d = dst[e];
  int pos = atomicAdd(&cnt[d], 1);
  if (pos < CAP - 1) wbucket[d * CAP + pos].x = s;   // keep one slot for self
}

// merged prep+wb: weight buckets (dinv inline from cnt), gstart scan, Wt
// transposes -- one launch instead of two, no dinv buffer.
// bucket: slots [0,m) = (src, dinv[s]*dinv[d]); slot m = (d, dinv[d]^2)
// self-loop; slots (m, mp) = (d, 0) pads to x4 boundary.
__global__ void k_wb(const int* __restrict__ cnt, const int* __restrict__ batch,
                     int* gstart,
                     const float* __restrict__ W1, const float* __restrict__ W2,
                     const float* __restrict__ W3,
                     __bf16* __restrict__ Wt1, __bf16* __restrict__ Wt2,
                     __bf16* __restrict__ Wt3, int2* __restrict__ wbucket) {
  int gid = blockIdx.x * 256 + threadIdx.x;
  if (gid < 3 * 16384) {
    int which = gid >> 14, idx = gid & 16383;
    int n = idx >> 7, k = idx & 127;
    const float* W = (which == 0) ? W1 : (which == 1) ? W2 : W3;
    __bf16* Wt = (which == 0) ? Wt1 : (which == 1) ? Wt2 : Wt3;
    Wt[(size_t)n * 128 + k] = (__bf16)W[(size_t)k * 128 + n];
  }
  if (gid < NN) {
    int b = batch[gid];
    if (gid == 0) {
      for (int g = 0; g <= b; ++g) gstart[g] = 0;
    } else {
      int prev = batch[gid - 1];
      for (int g = prev + 1; g <= b; ++g) gstart[g] = gid;
    }
  }
  if (gid < NN * CAP) {
    int d = gid >> 5, slot = gid & 31;
    int m = min(cnt[d], CAP - 1);
    int mp = (m + 4) & ~3;              // m+1 entries rounded up to x4
    if (slot < mp) {
      float dd = rsqrtf((float)(cnt[d] + 1));
      int s; float w;
      if (slot < m)      { s = wbucket[gid].x; w = rsqrtf((float)(cnt[s] + 1)) * dd; }
      else if (slot == m){ s = d;              w = dd * dd; }
      else               { s = d;              w = 0.f; }
      wbucket[gid] = make_int2(s, __float_as_int(w));
    }
  }
}

// ---------------- fused layer 0: h0 = relu(Agg(x) @ W0 + b0) -> bf16 -----
// 16 threads per node (one per 8-col group). All 16 lanes of a node walk the
// same bucket slots -> identical addresses coalesce to broadcasts.
__global__ void k_l0(const float4* __restrict__ x, const int* __restrict__ cnt,
                     const int2* __restrict__ wbucket,
                     const float* __restrict__ W0, const float* __restrict__ b0,
                     u32* __restrict__ hout2) {
  int gid = blockIdx.x * 256 + threadIdx.x;
  if (gid >= NN * 16) return;
  int node = gid >> 4, cg = gid & 15;
  int m1 = min(cnt[node], CAP - 1) + 1;  // edges + self
  float4 yv = make_float4(0.f, 0.f, 0.f, 0.f);
  for (int e = 0; e < m1; ++e) {
    int2 md = wbucket[(size_t)node * CAP + e];   // broadcast across the 16 lanes
    float wgt = __int_as_float(md.y);
    float4 v = x[md.x];
    yv.x = fmaf(wgt, v.x, yv.x);
    yv.y = fmaf(wgt, v.y, yv.y);
    yv.z = fmaf(wgt, v.z, yv.z);
    yv.w = fmaf(wgt, v.w, yv.w);
  }
  float v[8];
  #pragma unroll
  for (int k = 0; k < 2; ++k) {
    float4 b = *(const float4*)(b0 + cg * 8 + k * 4);
    v[k * 4 + 0] = b.x; v[k * 4 + 1] = b.y; v[k * 4 + 2] = b.z; v[k * 4 + 3] = b.w;
  }
  #pragma unroll
  for (int k = 0; k < 4; ++k) {
    float yk = (k == 0) ? yv.x : (k == 1) ? yv.y : (k == 2) ? yv.z : yv.w;
    float4 wa = *(const float4*)(W0 + k * 128 + cg * 8);
    float4 wb = *(const float4*)(W0 + k * 128 + cg * 8 + 4);
    v[0] = fmaf(yk, wa.x, v[0]); v[1] = fmaf(yk, wa.y, v[1]);
    v[2] = fmaf(yk, wa.z, v[2]); v[3] = fmaf(yk, wa.w, v[3]);
    v[4] = fmaf(yk, wb.x, v[4]); v[5] = fmaf(yk, wb.y, v[5]);
    v[6] = fmaf(yk, wb.z, v[6]); v[7] = fmaf(yk, wb.w, v[7]);
  }
  uint4 o;
  o.x = f2_to_bf2(fmaxf(v[0], 0.f), fmaxf(v[1], 0.f));
  o.y = f2_to_bf2(fmaxf(v[2], 0.f), fmaxf(v[3], 0.f));
  o.z = f2_to_bf2(fmaxf(v[4], 0.f), fmaxf(v[5], 0.f));
  o.w = f2_to_bf2(fmaxf(v[6], 0.f), fmaxf(v[7], 0.f));
  *(uint4*)(hout2 + (size_t)node * 64 + cg * 4) = o;
}

// ---------------- g = Agg(h): 128-dim bf16 gather, 2 nodes/wave ----------
// Masked slot-table load: only lanes < mp fetch their slot (saves ~half the
// wbucket cache lines). x4 padding; 8-wide main loop (16 rows in flight).
__global__ __launch_bounds__(256) void k_agg23(const __bf16* __restrict__ hlin,
                                               const int* __restrict__ cnt,
                                               const int2* __restrict__ wbucket,
                                               u32* __restrict__ hout2) {
  int wid = (blockIdx.x * 4) + (threadIdx.x >> 6);   // wave id
  int lane = threadIdx.x & 63;
  int ln = lane & 15, quad = lane >> 4;
  int na = wid * 2, nb = wid * 2 + 1;
  if (na >= NN) return;

  int mpa = (min(cnt[na], CAP - 1) + 4) & ~3;
  int mpb = (nb < NN) ? ((min(cnt[nb], CAP - 1) + 4) & ~3) : 0;
  int mpmin = min(mpa, mpb);

  int nodeL = (lane < 32) ? na : nb;
  int slot = lane & 31;
  int mymp = (lane < 32) ? mpa : mpb;
  int2 me = make_int2(0, 0);
  if (slot < mymp) me = wbucket[(size_t)nodeL * CAP + slot];  // masked: skip dead lines
  int s_l = me.x, w_l = me.y;

  float aa[8] = {0.f, 0.f, 0.f, 0.f, 0.f, 0.f, 0.f, 0.f};
  float ab[8] = {0.f, 0.f, 0.f, 0.f, 0.f, 0.f, 0.f, 0.f};

  int j = 0;
  for (; j + 8 <= mpmin; j += 8) {
    // full-ILP dual-node step: 16 rows in flight
    int p0 = (j + quad) * 4, p1 = (j + 4 + quad) * 4;
    int sa0 = __builtin_amdgcn_ds_bpermute(p0, s_l);
    int sa1 = __builtin_amdgcn_ds_bpermute(p1, s_l);
    int sb0 = __builtin_amdgcn_ds_bpermute(128 + p0, s_l);
    int sb1 = __builtin_amdgcn_ds_bpermute(128 + p1, s_l);
    float wa0 = __int_as_float(__builtin_amdgcn_ds_bpermute(p0, w_l));
    float wa1 = __int_as_float(__builtin_amdgcn_ds_bpermute(p1, w_l));
    float wb0 = __int_as_float(__builtin_amdgcn_ds_bpermute(128 + p0, w_l));
    float wb1 = __int_as_float(__builtin_amdgcn_ds_bpermute(128 + p1, w_l));
    uint4 ua0 = *(const uint4*)(hlin + ((size_t)sa0 << 7) + ln * 8);
    uint4 ua1 = *(const uint4*)(hlin + ((size_t)sa1 << 7) + ln * 8);
    uint4 ub0 = *(const uint4*)(hlin + ((size_t)sb0 << 7) + ln * 8);
    uint4 ub1 = *(const uint4*)(hlin + ((size_t)sb1 << 7) + ln * 8);
    float2 f;
    f = bf2_to_f2(ua0.x); aa[0] = fmaf(wa0, f.x, aa[0]); aa[1] = fmaf(wa0, f.y, aa[1]);
    f = bf2_to_f2(ua0.y); aa[2] = fmaf(wa0, f.x, aa[2]); aa[3] = fmaf(wa0, f.y, aa[3]);
    f = bf2_to_f2(ua0.z); aa[4] = fmaf(wa0, f.x, aa[4]); aa[5] = fmaf(wa0, f.y, aa[5]);
    f = bf2_to_f2(ua0.w); aa[6] = fmaf(wa0, f.x, aa[6]); aa[7] = fmaf(wa0, f.y, aa[7]);
    f = bf2_to_f2(ua1.x); aa[0] = fmaf(wa1, f.x, aa[0]); aa[1] = fmaf(wa1, f.y, aa[1]);
    f = bf2_to_f2(ua1.y); aa[2] = fmaf(wa1, f.x, aa[2]); aa[3] = fmaf(wa1, f.y, aa[3]);
    f = bf2_to_f2(ua1.z); aa[4] = fmaf(wa1, f.x, aa[4]); aa[5] = fmaf(wa1, f.y, aa[5]);
    f = bf2_to_f2(ua1.w); aa[6] = fmaf(wa1, f.x, aa[6]); aa[7] = fmaf(wa1, f.y, aa[7]);
    f = bf2_to_f2(ub0.x); ab[0] = fmaf(wb0, f.x, ab[0]); ab[1] = fmaf(wb0, f.y, ab[1]);
    f = bf2_to_f2(ub0.y); ab[2] = fmaf(wb0, f.x, ab[2]); ab[3] = fmaf(wb0, f.y, ab[3]);
    f = bf2_to_f2(ub0.z); ab[4] = fmaf(wb0, f.x, ab[4]); ab[5] = fmaf(wb0, f.y, ab[5]);
    f = bf2_to_f2(ub0.w); ab[6] = fmaf(wb0, f.x, ab[6]); ab[7] = fmaf(wb0, f.y, ab[7]);
    f = bf2_to_f2(ub1.x); ab[0] = fmaf(wb1, f.x, ab[0]); ab[1] = fmaf(wb1, f.y, ab[1]);
    f = bf2_to_f2(ub1.y); ab[2] = fmaf(wb1, f.x, ab[2]); ab[3] = fmaf(wb1, f.y, ab[3]);
    f = bf2_to_f2(ub1.z); ab[4] = fmaf(wb1, f.x, ab[4]); ab[5] = fmaf(wb1, f.y, ab[5]);
    f = bf2_to_f2(ub1.w); ab[6] = fmaf(wb1, f.x, ab[6]); ab[7] = fmaf(wb1, f.y, ab[7]);
  }
  if (j < mpmin) {
    // 4-wide dual-node remainder (mpmin - j == 4)
    int p = (j + quad) * 4;
    int sa = __builtin_amdgcn_ds_bpermute(p, s_l);
    int sb = __builtin_amdgcn_ds_bpermute(128 + p, s_l);
    float wa = __int_as_float(__builtin_amdgcn_ds_bpermute(p, w_l));
    float wb = __int_as_float(__builtin_amdgcn_ds_bpermute(128 + p, w_l));
    uint4 ua = *(const uint4*)(hlin + ((size_t)sa << 7) + ln * 8);
    uint4 ub = *(const uint4*)(hlin + ((size_t)sb << 7) + ln * 8);
    float2 f;
    f = bf2_to_f2(ua.x); aa[0] = fmaf(wa, f.x, aa[0]); aa[1] = fmaf(wa, f.y, aa[1]);
    f = bf2_to_f2(ua.y); aa[2] = fmaf(wa, f.x, aa[2]); aa[3] = fmaf(wa, f.y, aa[3]);
    f = bf2_to_f2(ua.z); aa[4] = fmaf(wa, f.x, aa[4]); aa[5] = fmaf(wa, f.y, aa[5]);
    f = bf2_to_f2(ua.w); aa[6] = fmaf(wa, f.x, aa[6]); aa[7] = fmaf(wa, f.y, aa[7]);
    f = bf2_to_f2(ub.x); ab[0] = fmaf(wb, f.x, ab[0]); ab[1] = fmaf(wb, f.y, ab[1]);
    f = bf2_to_f2(ub.y); ab[2] = fmaf(wb, f.x, ab[2]); ab[3] = fmaf(wb, f.y, ab[3]);
    f = bf2_to_f2(ub.z); ab[4] = fmaf(wb, f.x, ab[4]); ab[5] = fmaf(wb, f.y, ab[5]);
    f = bf2_to_f2(ub.w); ab[6] = fmaf(wb, f.x, ab[6]); ab[7] = fmaf(wb, f.y, ab[7]);
    j += 4;
  }
  // tails, 4-wide (exactly one of these loops runs)
  for (; j < mpa; j += 4) {
    int p = (j + quad) * 4;
    int s0 = __builtin_amdgcn_ds_bpermute(p, s_l);
    float w0 = __int_as_float(__builtin_amdgcn_ds_bpermute(p, w_l));
    uint4 u0 = *(const uint4*)(hlin + ((size_t)s0 << 7) + ln * 8);
    float2 f;
    f = bf2_to_f2(u0.x); aa[0] = fmaf(w0, f.x, aa[0]); aa[1] = fmaf(w0, f.y, aa[1]);
    f = bf2_to_f2(u0.y); aa[2] = fmaf(w0, f.x, aa[2]); aa[3] = fmaf(w0, f.y, aa[3]);
    f = bf2_to_f2(u0.z); aa[4] = fmaf(w0, f.x, aa[4]); aa[5] = fmaf(w0, f.y, aa[5]);
    f = bf2_to_f2(u0.w); aa[6] = fmaf(w0, f.x, aa[6]); aa[7] = fmaf(w0, f.y, aa[7]);
  }
  for (; j < mpb; j += 4) {
    int p = 128 + (j + quad) * 4;
    int s0 = __builtin_amdgcn_ds_bpermute(p, s_l);
    float w0 = __int_as_float(__builtin_amdgcn_ds_bpermute(p, w_l));
    uint4 u0 = *(const uint4*)(hlin + ((size_t)s0 << 7) + ln * 8);
    float2 f;
    f = bf2_to_f2(u0.x); ab[0] = fmaf(w0, f.x, ab[0]); ab[1] = fmaf(w0, f.y, ab[1]);
    f = bf2_to_f2(u0.y); ab[2] = fmaf(w0, f.x, ab[2]); ab[3] = fmaf(w0, f.y, ab[3]);
    f = bf2_to_f2(u0.z); ab[4] = fmaf(w0, f.x, ab[4]); ab[5] = fmaf(w0, f.y, ab[5]);
    f = bf2_to_f2(u0.w); ab[6] = fmaf(w0, f.x, ab[6]); ab[7] = fmaf(w0, f.y, ab[7]);
  }

  #pragma unroll
  for (int k = 0; k < 8; ++k) {
    aa[k] += __shfl_xor(aa[k], 16); aa[k] += __shfl_xor(aa[k], 32);
    ab[k] += __shfl_xor(ab[k], 16); ab[k] += __shfl_xor(ab[k], 32);
  }
  if (quad == 0) {
    uint4 oa;
    oa.x = f2_to_bf2(aa[0], aa[1]); oa.y = f2_to_bf2(aa[2], aa[3]);
    oa.z = f2_to_bf2(aa[4], aa[5]); oa.w = f2_to_bf2(aa[6], aa[7]);
    *(uint4*)(hout2 + (size_t)na * 64 + ln * 4) = oa;
    if (nb < NN) {
      uint4 ob;
      ob.x = f2_to_bf2(ab[0], ab[1]); ob.y = f2_to_bf2(ab[2], ab[3]);
      ob.z = f2_to_bf2(ab[4], ab[5]); ob.w = f2_to_bf2(ab[6], ab[7]);
      *(uint4*)(hout2 + (size_t)nb * 64 + ln * 4) = ob;
    }
  }
}

// ---------------- MFMA GEMM: h' = relu(g @ W + b), layers 1-2 ------------
__global__ __launch_bounds__(256) void k_mfma(const __bf16* __restrict__ hin,
                                              const __bf16* __restrict__ Wt,
                                              const float* __restrict__ bias,
                                              __bf16* __restrict__ hout) {
  __shared__ __bf16 As[128 * LDSPAD];   // 34 KB
  int tid = threadIdx.x;
  int row0 = blockIdx.x * 128;
  int lane = tid & 63, w = tid >> 6;
  int ln = lane & 15, quad = lane >> 4;

  bf16x8 bfrag[8][4];
  float bcol[8];
  #pragma unroll
  for (int nt = 0; nt < 8; ++nt) {
    bcol[nt] = bias[nt * 16 + ln];
    #pragma unroll
    for (int kc = 0; kc < 4; ++kc)
      bfrag[nt][kc] = *(const bf16x8*)(Wt + (size_t)(nt * 16 + ln) * 128 + kc * 32 + quad * 8);
  }

  #pragma unroll
  for (int i = 0; i < 8; ++i) {
    int eb = (i * 256 + tid) * 8;
    int r = eb >> 7, c = eb & 127;
    int gr = row0 + r;
    uint4 v = make_uint4(0, 0, 0, 0);
    if (gr < NN) v = *(const uint4*)(hin + (size_t)gr * 128 + c);
    *(uint4*)&As[r * LDSPAD + c] = v;
  }
  __syncthreads();

  f32x4 acc[2][8];
  #pragma unroll
  for (int rt = 0; rt < 2; ++rt)
    #pragma unroll
    for (int nt = 0; nt < 8; ++nt) acc[rt][nt] = (f32x4){0.f, 0.f, 0.f, 0.f};

  #pragma unroll
  for (int kc = 0; kc < 4; ++kc) {
    bf16x8 a0 = *(const bf16x8*)&As[(w * 32 + ln) * LDSPAD + kc * 32 + quad * 8];
    bf16x8 a1 = *(const bf16x8*)&As[(w * 32 + 16 + ln) * LDSPAD + kc * 32 + quad * 8];
    #pragma unroll
    for (int nt = 0; nt < 8; ++nt) {
      acc[0][nt] = __builtin_amdgcn_mfma_f32_16x16x32_bf16(a0, bfrag[nt][kc], acc[0][nt], 0, 0, 0);
      acc[1][nt] = __builtin_amdgcn_mfma_f32_16x16x32_bf16(a1, bfrag[nt][kc], acc[1][nt], 0, 0, 0);
    }
  }

  // C layout: row=(lane>>4)*4+reg, col=lane&15; epilogue = +bias, relu
  #pragma unroll
  for (int rt = 0; rt < 2; ++rt)
    #pragma unroll
    for (int nt = 0; nt < 8; ++nt)
      #pragma unroll
      for (int reg = 0; reg < 4; ++reg) {
        int gr = row0 + w * 32 + rt * 16 + quad * 4 + reg;
        if (gr < NN)
          hout[(size_t)gr * 128 + nt * 16 + ln] =
              (__bf16)fmaxf(acc[rt][nt][reg] + bcol[nt], 0.f);
      }
}

// ---------------- layer-3 MFMA with fused mean-pool -----------------------
// h3 = relu(g@W3+b3) is only consumed by the mean pool, so never materialize
// it: the epilogue wave-reduces each 16-row tile (batch sorted -> tiles are
// graph-uniform except at boundaries) and atomicAdds fp32 partials.
__global__ __launch_bounds__(256) void k_mfma_pool(const __bf16* __restrict__ hin,
                                                   const __bf16* __restrict__ Wt,
                                                   const float* __restrict__ bias,
                                                   const int* __restrict__ batch,
                                                   float* __restrict__ sums) {
  __shared__ __bf16 As[128 * LDSPAD];   // 34 KB
  int tid = threadIdx.x;
  int row0 = blockIdx.x * 128;
  int lane = tid & 63, w = tid >> 6;
  int ln = lane & 15, quad = lane >> 4;

  bf16x8 bfrag[8][4];
  float bcol[8];
  #pragma unroll
  for (int nt = 0; nt < 8; ++nt) {
    bcol[nt] = bias[nt * 16 + ln];
    #pragma unroll
    for (int kc = 0; kc < 4; ++kc)
      bfrag[nt][kc] = *(const bf16x8*)(Wt + (size_t)(nt * 16 + ln) * 128 + kc * 32 + quad * 8);
  }

  #pragma unroll
  for (int i = 0; i < 8; ++i) {
    int eb = (i * 256 + tid) * 8;
    int r = eb >> 7, c = eb & 127;
    int gr = row0 + r;
    uint4 v = make_uint4(0, 0, 0, 0);
    if (gr < NN) v = *(const uint4*)(hin + (size_t)gr * 128 + c);
    *(uint4*)&As[r * LDSPAD + c] = v;
  }
  __syncthreads();

  f32x4 acc[2][8];
  #pragma unroll
  for (int rt = 0; rt < 2; ++rt)
    #pragma unroll
    for (int nt = 0; nt < 8; ++nt) acc[rt][nt] = (f32x4){0.f, 0.f, 0.f, 0.f};

  #pragma unroll
  for (int kc = 0; kc < 4; ++kc) {
    bf16x8 a0 = *(const bf16x8*)&As[(w * 32 + ln) * LDSPAD + kc * 32 + quad * 8];
    bf16x8 a1 = *(const bf16x8*)&As[(w * 32 + 16 + ln) * LDSPAD + kc * 32 + quad * 8];
    #pragma unroll
    for (int nt = 0; nt < 8; ++nt) {
      acc[0][nt] = __builtin_amdgcn_mfma_f32_16x16x32_bf16(a0, bfrag[nt][kc], acc[0][nt], 0, 0, 0);
      acc[1][nt] = __builtin_amdgcn_mfma_f32_16x16x32_bf16(a1, bfrag[nt][kc], acc[1][nt], 0, 0, 0);
    }
  }

  // epilogue: relu(acc+b) summed per graph. C row = quad*4+reg within the
  // 16-row tile; col = nt*16+ln.
  #pragma unroll
  for (int rt = 0; rt < 2; ++rt) {
    int tr0 = row0 + w * 32 + rt * 16;
    int trL = tr0 + 15;
    bool uni = (trL < NN) && (batch[tr0] == batch[trL]);   // wave-uniform
    if (uni) {
      int b0 = batch[tr0];
      #pragma unroll
      for (int nt = 0; nt < 8; ++nt) {
        float s = 0.f;
        #pragma unroll
        for (int reg = 0; reg < 4; ++reg)
          s += fmaxf(acc[rt][nt][reg] + bcol[nt], 0.f);
        s += __shfl_xor(s, 16);   // sum over quads -> 16-row tile total
        s += __shfl_xor(s, 32);
        if (quad == 0)
          atomicAdd(&sums[b0 * 128 + nt * 16 + ln], s);
      }
    } else {
      int bg[4]; bool ok[4];
      #pragma unroll
      for (int reg = 0; reg < 4; ++reg) {
        int gr = tr0 + quad * 4 + reg;
        ok[reg] = gr < NN;
        bg[reg] = ok[reg] ? batch[gr] : 0;
      }
      #pragma unroll
      for (int nt = 0; nt < 8; ++nt)
        #pragma unroll
        for (int reg = 0; reg < 4; ++reg)
          if (ok[reg])
            atomicAdd(&sums[bg[reg] * 128 + nt * 16 + ln],
                      fmaxf(acc[rt][nt][reg] + bcol[nt], 0.f));
    }
  }
}

// ---------------- head MLP over pooled sums ----------------
__global__ __launch_bounds__(64) void k_head(const float* __restrict__ sums,
                                             const int* __restrict__ gstart,
                                             const float* __restrict__ xs,
                                             const float* __restrict__ Wl1,
                                             const float* __restrict__ bl1,
                                             const float* __restrict__ Wl2,
                                             const float* __restrict__ bl2,
                                             float* __restrict__ out) {
  int g = blockIdx.x, tid = threadIdx.x;
  int beg = gstart[g], end = gstart[g + 1];
  float sc = 1.f / fmaxf((float)(end - beg), 1.f);
  float hj = bl1[tid];
  #pragma unroll 4
  for (int k = 0; k < 128; ++k)
    hj = fmaf(sums[g * 128 + k] * sc, Wl1[k * 64 + tid], hj);
  const float* xr = xs + g * 4;
  #pragma unroll
  for (int k = 0; k < 4; ++k) hj = fmaf(xr[k], Wl1[(128 + k) * 64 + tid], hj);
  hj = fmaxf(hj, 0.f);
  float val = hj * Wl2[tid];
  #pragma unroll
  for (int off = 32; off > 0; off >>= 1) val += __shfl_down(val, off);
  if (tid == 0) out[g] = val + bl2[0];
}

// ---------------- launcher ----------------

extern "C" void kernel_launch(void* const* d_in, const int* in_sizes, int n_in,
                              void* d_out, int out_size, void* d_ws, size_t ws_size,
                              hipStream_t stream) {
  const float* x    = (const float*)d_in[0];
  const int*   ei   = (const int*)d_in[1];
  const float* xs   = (const float*)d_in[2];
  const int*   batch= (const int*)d_in[3];
  const float* W0   = (const float*)d_in[4];
  const float* b0   = (const float*)d_in[5];
  const float* W1   = (const float*)d_in[6];
  const float* b1   = (const float*)d_in[7];
  const float* W2   = (const float*)d_in[8];
  const float* b2   = (const float*)d_in[9];
  const float* W3   = (const float*)d_in[10];
  const float* b3   = (const float*)d_in[11];
  const float* Wl1  = (const float*)d_in[12];
  const float* bl1  = (const float*)d_in[13];
  const float* Wl2  = (const float*)d_in[14];
  const float* bl2  = (const float*)d_in[15];
  const int* srcA = ei;        // edge_index[0]
  const int* dstA = ei + EE;   // edge_index[1]
  float* out = (float*)d_out;

  char* p = (char*)d_ws;
  auto take = [&](size_t bytes) { char* q = p; p += (bytes + 255) & ~(size_t)255; return q; };
  __bf16* hA    = (__bf16*)take((size_t)NN * 128 * 2);
  __bf16* hB    = (__bf16*)take((size_t)NN * 128 * 2);
  int*    cnt   = (int*)take((size_t)NN * 4);
  int2*   wbucket = (int2*)take((size_t)NN * CAP * 8);
  int*    gstart= (int*)take((size_t)(GG + 1) * 4);
  float*  sums  = (float*)take((size_t)GG * 128 * 4);
  __bf16* Wt1   = (__bf16*)take(16384 * 2);
  __bf16* Wt2   = (__bf16*)take(16384 * 2);
  __bf16* Wt3   = (__bf16*)take(16384 * 2);

  // setup
  k_init<<<INITB, 256, 0, stream>>>(cnt, gstart, sums);
  k_fill<<<(EE + 255) / 256, 256, 0, stream>>>(srcA, dstA, cnt, wbucket);
  k_wb<<<(NN * CAP + 255) / 256, 256, 0, stream>>>(cnt, batch, gstart, W1, W2, W3,
                                                   Wt1, Wt2, Wt3, wbucket);

  // layer 0 fused: h0 = relu(Agg(x)@W0+b0) materialized bf16
  k_l0<<<(NN * 16 + 255) / 256, 256, 0, stream>>>((const float4*)x, cnt, wbucket, W0, b0, (u32*)hA);
  // layers 1-2: g = Agg(h), h' = relu(g@W+b)
  k_agg23<<<(NN + 7) / 8, 256, 0, stream>>>(hA, cnt, wbucket, (u32*)hB);
  k_mfma<<<(NN + 127) / 128, 256, 0, stream>>>(hB, Wt1, b1, hA);
  k_agg23<<<(NN + 7) / 8, 256, 0, stream>>>(hA, cnt, wbucket, (u32*)hB);
  k_mfma<<<(NN + 127) / 128, 256, 0, stream>>>(hB, Wt2, b2, hA);
  // layer 3: GEMM with fused mean-pool (h3 never materialized)
  k_agg23<<<(NN + 7) / 8, 256, 0, stream>>>(hA, cnt, wbucket, (u32*)hB);
  k_mfma_pool<<<(NN + 127) / 128, 256, 0, stream>>>(hB, Wt3, b3, batch, sums);

  // head MLP over pooled sums
  k_head<<<GG, 64, 0, stream>>>(sums, gstart, xs, Wl1, bl1, Wl2, bl2, out);
}

// Round 6
// 348.481 us; speedup vs baseline: 1.0558x; 1.0558x over previous
//
#include <hip/hip_runtime.h>

#define NN 100000
#define EE 600000
#define GG 1000
#define NB ((NN + 255) / 256)
#define CAP 32          // bucket slots/node: up to 30 edges + self + pads (deg max ~25)
#define LDSPAD 136

typedef __bf16 bf16x8 __attribute__((ext_vector_type(8)));
typedef float f32x4 __attribute__((ext_vector_type(4)));
typedef unsigned int u32;

__device__ inline float2 bf2_to_f2(u32 u) {
  return make_float2(__uint_as_float(u << 16), __uint_as_float(u & 0xffff0000u));
}
__device__ inline u32 f2_to_bf2(float a, float b) {
  union { __bf16 h[2]; u32 u; } pk;
  pk.h[0] = (__bf16)a; pk.h[1] = (__bf16)b;
  return pk.u;
}

// ---------------- setup ----------------

__global__ void k_init(int* cnt, int* gstart) {
  int i = blockIdx.x * 256 + threadIdx.x;
  if (i < NN) cnt[i] = 0;
  if (i <= GG) gstart[i] = NN;
}

// writes src ids directly into wbucket.x (no separate ibucket buffer)
__global__ void k_fill(const int* __restrict__ src, const int* __restrict__ dst,
                       int* cnt, int2* __restrict__ wbucket) {
  int e = blockIdx.x * 256 + threadIdx.x;
  if (e >= EE) return;
  int s = src[e], d = dst[e];
  int pos = atomicAdd(&cnt[d], 1);
  if (pos < CAP - 1) wbucket[d * CAP + pos].x = s;   // keep one slot for self
}

// merged prep+wb: weight buckets (dinv inline from cnt), gstart scan, Wt
// transposes -- one launch, no dinv buffer.
// bucket: slots [0,m) = (src, dinv[s]*dinv[d]); slot m = (d, dinv[d]^2)
// self-loop; slots (m, mp) = (d, 0) pads to x4 boundary.
__global__ void k_wb(const int* __restrict__ cnt, const int* __restrict__ batch,
                     int* gstart,
                     const float* __restrict__ W1, const float* __restrict__ W2,
                     const float* __restrict__ W3,
                     __bf16* __restrict__ Wt1, __bf16* __restrict__ Wt2,
                     __bf16* __restrict__ Wt3, int2* __restrict__ wbucket) {
  int gid = blockIdx.x * 256 + threadIdx.x;
  if (gid < 3 * 16384) {
    int which = gid >> 14, idx = gid & 16383;
    int n = idx >> 7, k = idx & 127;
    const float* W = (which == 0) ? W1 : (which == 1) ? W2 : W3;
    __bf16* Wt = (which == 0) ? Wt1 : (which == 1) ? Wt2 : Wt3;
    Wt[(size_t)n * 128 + k] = (__bf16)W[(size_t)k * 128 + n];
  }
  if (gid < NN) {
    int b = batch[gid];
    if (gid == 0) {
      for (int g = 0; g <= b; ++g) gstart[g] = 0;
    } else {
      int prev = batch[gid - 1];
      for (int g = prev + 1; g <= b; ++g) gstart[g] = gid;
    }
  }
  if (gid < NN * CAP) {
    int d = gid >> 5, slot = gid & 31;
    int m = min(cnt[d], CAP - 1);
    int mp = (m + 4) & ~3;              // m+1 entries rounded up to x4
    if (slot < mp) {
      float dd = rsqrtf((float)(cnt[d] + 1));
      int s; float w;
      if (slot < m)      { s = wbucket[gid].x; w = rsqrtf((float)(cnt[s] + 1)) * dd; }
      else if (slot == m){ s = d;              w = dd * dd; }
      else               { s = d;              w = 0.f; }
      wbucket[gid] = make_int2(s, __float_as_int(w));
    }
  }
}

// ---------------- fused layer 0: h0 = relu(Agg(x) @ W0 + b0) -> bf16 -----
// 16 threads per node (one per 8-col group). All 16 lanes of a node walk the
// same bucket slots -> identical addresses coalesce to broadcasts.
__global__ void k_l0(const float4* __restrict__ x, const int* __restrict__ cnt,
                     const int2* __restrict__ wbucket,
                     const float* __restrict__ W0, const float* __restrict__ b0,
                     u32* __restrict__ hout2) {
  int gid = blockIdx.x * 256 + threadIdx.x;
  if (gid >= NN * 16) return;
  int node = gid >> 4, cg = gid & 15;
  int m1 = min(cnt[node], CAP - 1) + 1;  // edges + self
  float4 yv = make_float4(0.f, 0.f, 0.f, 0.f);
  for (int e = 0; e < m1; ++e) {
    int2 md = wbucket[(size_t)node * CAP + e];   // broadcast across the 16 lanes
    float wgt = __int_as_float(md.y);
    float4 v = x[md.x];
    yv.x = fmaf(wgt, v.x, yv.x);
    yv.y = fmaf(wgt, v.y, yv.y);
    yv.z = fmaf(wgt, v.z, yv.z);
    yv.w = fmaf(wgt, v.w, yv.w);
  }
  float v[8];
  #pragma unroll
  for (int k = 0; k < 2; ++k) {
    float4 b = *(const float4*)(b0 + cg * 8 + k * 4);
    v[k * 4 + 0] = b.x; v[k * 4 + 1] = b.y; v[k * 4 + 2] = b.z; v[k * 4 + 3] = b.w;
  }
  #pragma unroll
  for (int k = 0; k < 4; ++k) {
    float yk = (k == 0) ? yv.x : (k == 1) ? yv.y : (k == 2) ? yv.z : yv.w;
    float4 wa = *(const float4*)(W0 + k * 128 + cg * 8);
    float4 wb = *(const float4*)(W0 + k * 128 + cg * 8 + 4);
    v[0] = fmaf(yk, wa.x, v[0]); v[1] = fmaf(yk, wa.y, v[1]);
    v[2] = fmaf(yk, wa.z, v[2]); v[3] = fmaf(yk, wa.w, v[3]);
    v[4] = fmaf(yk, wb.x, v[4]); v[5] = fmaf(yk, wb.y, v[5]);
    v[6] = fmaf(yk, wb.z, v[6]); v[7] = fmaf(yk, wb.w, v[7]);
  }
  uint4 o;
  o.x = f2_to_bf2(fmaxf(v[0], 0.f), fmaxf(v[1], 0.f));
  o.y = f2_to_bf2(fmaxf(v[2], 0.f), fmaxf(v[3], 0.f));
  o.z = f2_to_bf2(fmaxf(v[4], 0.f), fmaxf(v[5], 0.f));
  o.w = f2_to_bf2(fmaxf(v[6], 0.f), fmaxf(v[7], 0.f));
  *(uint4*)(hout2 + (size_t)node * 64 + cg * 4) = o;
}

// ---------------- g = Agg(h): 128-dim bf16 gather, 2 nodes/wave ----------
// Masked slot-table load: only lanes < mp fetch their slot (saves ~half the
// wbucket cache lines). x4 padding; 8-wide main loop (16 rows in flight).
__global__ __launch_bounds__(256) void k_agg23(const __bf16* __restrict__ hlin,
                                               const int* __restrict__ cnt,
                                               const int2* __restrict__ wbucket,
                                               u32* __restrict__ hout2) {
  int wid = (blockIdx.x * 4) + (threadIdx.x >> 6);   // wave id
  int lane = threadIdx.x & 63;
  int ln = lane & 15, quad = lane >> 4;
  int na = wid * 2, nb = wid * 2 + 1;
  if (na >= NN) return;

  int mpa = (min(cnt[na], CAP - 1) + 4) & ~3;
  int mpb = (nb < NN) ? ((min(cnt[nb], CAP - 1) + 4) & ~3) : 0;
  int mpmin = min(mpa, mpb);

  int nodeL = (lane < 32) ? na : nb;
  int slot = lane & 31;
  int mymp = (lane < 32) ? mpa : mpb;
  int2 me = make_int2(0, 0);
  if (slot < mymp) me = wbucket[(size_t)nodeL * CAP + slot];  // masked: skip dead lines
  int s_l = me.x, w_l = me.y;

  float aa[8] = {0.f, 0.f, 0.f, 0.f, 0.f, 0.f, 0.f, 0.f};
  float ab[8] = {0.f, 0.f, 0.f, 0.f, 0.f, 0.f, 0.f, 0.f};

  int j = 0;
  for (; j + 8 <= mpmin; j += 8) {
    // full-ILP dual-node step: 16 rows in flight
    int p0 = (j + quad) * 4, p1 = (j + 4 + quad) * 4;
    int sa0 = __builtin_amdgcn_ds_bpermute(p0, s_l);
    int sa1 = __builtin_amdgcn_ds_bpermute(p1, s_l);
    int sb0 = __builtin_amdgcn_ds_bpermute(128 + p0, s_l);
    int sb1 = __builtin_amdgcn_ds_bpermute(128 + p1, s_l);
    float wa0 = __int_as_float(__builtin_amdgcn_ds_bpermute(p0, w_l));
    float wa1 = __int_as_float(__builtin_amdgcn_ds_bpermute(p1, w_l));
    float wb0 = __int_as_float(__builtin_amdgcn_ds_bpermute(128 + p0, w_l));
    float wb1 = __int_as_float(__builtin_amdgcn_ds_bpermute(128 + p1, w_l));
    uint4 ua0 = *(const uint4*)(hlin + ((size_t)sa0 << 7) + ln * 8);
    uint4 ua1 = *(const uint4*)(hlin + ((size_t)sa1 << 7) + ln * 8);
    uint4 ub0 = *(const uint4*)(hlin + ((size_t)sb0 << 7) + ln * 8);
    uint4 ub1 = *(const uint4*)(hlin + ((size_t)sb1 << 7) + ln * 8);
    float2 f;
    f = bf2_to_f2(ua0.x); aa[0] = fmaf(wa0, f.x, aa[0]); aa[1] = fmaf(wa0, f.y, aa[1]);
    f = bf2_to_f2(ua0.y); aa[2] = fmaf(wa0, f.x, aa[2]); aa[3] = fmaf(wa0, f.y, aa[3]);
    f = bf2_to_f2(ua0.z); aa[4] = fmaf(wa0, f.x, aa[4]); aa[5] = fmaf(wa0, f.y, aa[5]);
    f = bf2_to_f2(ua0.w); aa[6] = fmaf(wa0, f.x, aa[6]); aa[7] = fmaf(wa0, f.y, aa[7]);
    f = bf2_to_f2(ua1.x); aa[0] = fmaf(wa1, f.x, aa[0]); aa[1] = fmaf(wa1, f.y, aa[1]);
    f = bf2_to_f2(ua1.y); aa[2] = fmaf(wa1, f.x, aa[2]); aa[3] = fmaf(wa1, f.y, aa[3]);
    f = bf2_to_f2(ua1.z); aa[4] = fmaf(wa1, f.x, aa[4]); aa[5] = fmaf(wa1, f.y, aa[5]);
    f = bf2_to_f2(ua1.w); aa[6] = fmaf(wa1, f.x, aa[6]); aa[7] = fmaf(wa1, f.y, aa[7]);
    f = bf2_to_f2(ub0.x); ab[0] = fmaf(wb0, f.x, ab[0]); ab[1] = fmaf(wb0, f.y, ab[1]);
    f = bf2_to_f2(ub0.y); ab[2] = fmaf(wb0, f.x, ab[2]); ab[3] = fmaf(wb0, f.y, ab[3]);
    f = bf2_to_f2(ub0.z); ab[4] = fmaf(wb0, f.x, ab[4]); ab[5] = fmaf(wb0, f.y, ab[5]);
    f = bf2_to_f2(ub0.w); ab[6] = fmaf(wb0, f.x, ab[6]); ab[7] = fmaf(wb0, f.y, ab[7]);
    f = bf2_to_f2(ub1.x); ab[0] = fmaf(wb1, f.x, ab[0]); ab[1] = fmaf(wb1, f.y, ab[1]);
    f = bf2_to_f2(ub1.y); ab[2] = fmaf(wb1, f.x, ab[2]); ab[3] = fmaf(wb1, f.y, ab[3]);
    f = bf2_to_f2(ub1.z); ab[4] = fmaf(wb1, f.x, ab[4]); ab[5] = fmaf(wb1, f.y, ab[5]);
    f = bf2_to_f2(ub1.w); ab[6] = fmaf(wb1, f.x, ab[6]); ab[7] = fmaf(wb1, f.y, ab[7]);
  }
  if (j < mpmin) {
    // 4-wide dual-node remainder (mpmin - j == 4)
    int p = (j + quad) * 4;
    int sa = __builtin_amdgcn_ds_bpermute(p, s_l);
    int sb = __builtin_amdgcn_ds_bpermute(128 + p, s_l);
    float wa = __int_as_float(__builtin_amdgcn_ds_bpermute(p, w_l));
    float wb = __int_as_float(__builtin_amdgcn_ds_bpermute(128 + p, w_l));
    uint4 ua = *(const uint4*)(hlin + ((size_t)sa << 7) + ln * 8);
    uint4 ub = *(const uint4*)(hlin + ((size_t)sb << 7) + ln * 8);
    float2 f;
    f = bf2_to_f2(ua.x); aa[0] = fmaf(wa, f.x, aa[0]); aa[1] = fmaf(wa, f.y, aa[1]);
    f = bf2_to_f2(ua.y); aa[2] = fmaf(wa, f.x, aa[2]); aa[3] = fmaf(wa, f.y, aa[3]);
    f = bf2_to_f2(ua.z); aa[4] = fmaf(wa, f.x, aa[4]); aa[5] = fmaf(wa, f.y, aa[5]);
    f = bf2_to_f2(ua.w); aa[6] = fmaf(wa, f.x, aa[6]); aa[7] = fmaf(wa, f.y, aa[7]);
    f = bf2_to_f2(ub.x); ab[0] = fmaf(wb, f.x, ab[0]); ab[1] = fmaf(wb, f.y, ab[1]);
    f = bf2_to_f2(ub.y); ab[2] = fmaf(wb, f.x, ab[2]); ab[3] = fmaf(wb, f.y, ab[3]);
    f = bf2_to_f2(ub.z); ab[4] = fmaf(wb, f.x, ab[4]); ab[5] = fmaf(wb, f.y, ab[5]);
    f = bf2_to_f2(ub.w); ab[6] = fmaf(wb, f.x, ab[6]); ab[7] = fmaf(wb, f.y, ab[7]);
    j += 4;
  }
  // tails, 4-wide (exactly one of these loops runs)
  for (; j < mpa; j += 4) {
    int p = (j + quad) * 4;
    int s0 = __builtin_amdgcn_ds_bpermute(p, s_l);
    float w0 = __int_as_float(__builtin_amdgcn_ds_bpermute(p, w_l));
    uint4 u0 = *(const uint4*)(hlin + ((size_t)s0 << 7) + ln * 8);
    float2 f;
    f = bf2_to_f2(u0.x); aa[0] = fmaf(w0, f.x, aa[0]); aa[1] = fmaf(w0, f.y, aa[1]);
    f = bf2_to_f2(u0.y); aa[2] = fmaf(w0, f.x, aa[2]); aa[3] = fmaf(w0, f.y, aa[3]);
    f = bf2_to_f2(u0.z); aa[4] = fmaf(w0, f.x, aa[4]); aa[5] = fmaf(w0, f.y, aa[5]);
    f = bf2_to_f2(u0.w); aa[6] = fmaf(w0, f.x, aa[6]); aa[7] = fmaf(w0, f.y, aa[7]);
  }
  for (; j < mpb; j += 4) {
    int p = 128 + (j + quad) * 4;
    int s0 = __builtin_amdgcn_ds_bpermute(p, s_l);
    float w0 = __int_as_float(__builtin_amdgcn_ds_bpermute(p, w_l));
    uint4 u0 = *(const uint4*)(hlin + ((size_t)s0 << 7) + ln * 8);
    float2 f;
    f = bf2_to_f2(u0.x); ab[0] = fmaf(w0, f.x, ab[0]); ab[1] = fmaf(w0, f.y, ab[1]);
    f = bf2_to_f2(u0.y); ab[2] = fmaf(w0, f.x, ab[2]); ab[3] = fmaf(w0, f.y, ab[3]);
    f = bf2_to_f2(u0.z); ab[4] = fmaf(w0, f.x, ab[4]); ab[5] = fmaf(w0, f.y, ab[5]);
    f = bf2_to_f2(u0.w); ab[6] = fmaf(w0, f.x, ab[6]); ab[7] = fmaf(w0, f.y, ab[7]);
  }

  #pragma unroll
  for (int k = 0; k < 8; ++k) {
    aa[k] += __shfl_xor(aa[k], 16); aa[k] += __shfl_xor(aa[k], 32);
    ab[k] += __shfl_xor(ab[k], 16); ab[k] += __shfl_xor(ab[k], 32);
  }
  if (quad == 0) {
    uint4 oa;
    oa.x = f2_to_bf2(aa[0], aa[1]); oa.y = f2_to_bf2(aa[2], aa[3]);
    oa.z = f2_to_bf2(aa[4], aa[5]); oa.w = f2_to_bf2(aa[6], aa[7]);
    *(uint4*)(hout2 + (size_t)na * 64 + ln * 4) = oa;
    if (nb < NN) {
      uint4 ob;
      ob.x = f2_to_bf2(ab[0], ab[1]); ob.y = f2_to_bf2(ab[2], ab[3]);
      ob.z = f2_to_bf2(ab[4], ab[5]); ob.w = f2_to_bf2(ab[6], ab[7]);
      *(uint4*)(hout2 + (size_t)nb * 64 + ln * 4) = ob;
    }
  }
}

// ---------------- MFMA GEMM: h' = relu(g @ W + b), B-frags in registers ---
__global__ __launch_bounds__(256) void k_mfma(const __bf16* __restrict__ hin,
                                              const __bf16* __restrict__ Wt,
                                              const float* __restrict__ bias,
                                              __bf16* __restrict__ hout) {
  __shared__ __bf16 As[128 * LDSPAD];   // 34 KB
  int tid = threadIdx.x;
  int row0 = blockIdx.x * 128;
  int lane = tid & 63, w = tid >> 6;
  int ln = lane & 15, quad = lane >> 4;

  bf16x8 bfrag[8][4];
  float bcol[8];
  #pragma unroll
  for (int nt = 0; nt < 8; ++nt) {
    bcol[nt] = bias[nt * 16 + ln];
    #pragma unroll
    for (int kc = 0; kc < 4; ++kc)
      bfrag[nt][kc] = *(const bf16x8*)(Wt + (size_t)(nt * 16 + ln) * 128 + kc * 32 + quad * 8);
  }

  #pragma unroll
  for (int i = 0; i < 8; ++i) {
    int eb = (i * 256 + tid) * 8;
    int r = eb >> 7, c = eb & 127;
    int gr = row0 + r;
    uint4 v = make_uint4(0, 0, 0, 0);
    if (gr < NN) v = *(const uint4*)(hin + (size_t)gr * 128 + c);
    *(uint4*)&As[r * LDSPAD + c] = v;
  }
  __syncthreads();

  f32x4 acc[2][8];
  #pragma unroll
  for (int rt = 0; rt < 2; ++rt)
    #pragma unroll
    for (int nt = 0; nt < 8; ++nt) acc[rt][nt] = (f32x4){0.f, 0.f, 0.f, 0.f};

  #pragma unroll
  for (int kc = 0; kc < 4; ++kc) {
    bf16x8 a0 = *(const bf16x8*)&As[(w * 32 + ln) * LDSPAD + kc * 32 + quad * 8];
    bf16x8 a1 = *(const bf16x8*)&As[(w * 32 + 16 + ln) * LDSPAD + kc * 32 + quad * 8];
    #pragma unroll
    for (int nt = 0; nt < 8; ++nt) {
      acc[0][nt] = __builtin_amdgcn_mfma_f32_16x16x32_bf16(a0, bfrag[nt][kc], acc[0][nt], 0, 0, 0);
      acc[1][nt] = __builtin_amdgcn_mfma_f32_16x16x32_bf16(a1, bfrag[nt][kc], acc[1][nt], 0, 0, 0);
    }
  }

  // C layout: row=(lane>>4)*4+reg, col=lane&15; epilogue = +bias, relu
  #pragma unroll
  for (int rt = 0; rt < 2; ++rt)
    #pragma unroll
    for (int nt = 0; nt < 8; ++nt)
      #pragma unroll
      for (int reg = 0; reg < 4; ++reg) {
        int gr = row0 + w * 32 + rt * 16 + quad * 4 + reg;
        if (gr < NN)
          hout[(size_t)gr * 128 + nt * 16 + ln] =
              (__bf16)fmaxf(acc[rt][nt][reg] + bcol[nt], 0.f);
      }
}

// ---------------- fused pool + MLP head ----------------
__global__ __launch_bounds__(256) void k_poolmlp(const uint2* __restrict__ h4u,
                                                 const int* __restrict__ gstart,
                                                 const float* __restrict__ xs,
                                                 const float* __restrict__ Wl1,
                                                 const float* __restrict__ bl1,
                                                 const float* __restrict__ Wl2,
                                                 const float* __restrict__ bl2,
                                                 float* __restrict__ out) {
  __shared__ float4 part[8][32];
  __shared__ float pooled[128];
  int g = blockIdx.x;
  int beg = gstart[g], end = gstart[g + 1];
  int tid = threadIdx.x;
  int cg = tid & 31;
  int rg = tid >> 5;
  float4 acc = make_float4(0.f, 0.f, 0.f, 0.f);
  for (int i = beg + rg; i < end; i += 8) {
    uint2 u = h4u[(size_t)i * 32 + cg];
    acc.x += __uint_as_float(u.x << 16);
    acc.y += __uint_as_float(u.x & 0xffff0000u);
    acc.z += __uint_as_float(u.y << 16);
    acc.w += __uint_as_float(u.y & 0xffff0000u);
  }
  part[rg][cg] = acc;
  __syncthreads();
  if (tid < 32) {
    float4 s = part[0][tid];
    #pragma unroll
    for (int r = 1; r < 8; ++r) {
      float4 v = part[r][tid];
      s.x += v.x; s.y += v.y; s.z += v.z; s.w += v.w;
    }
    float sc = 1.f / fmaxf((float)(end - beg), 1.f);
    pooled[tid * 4 + 0] = s.x * sc;
    pooled[tid * 4 + 1] = s.y * sc;
    pooled[tid * 4 + 2] = s.z * sc;
    pooled[tid * 4 + 3] = s.w * sc;
  }
  __syncthreads();
  if (tid < 64) {
    float hj = bl1[tid];
    #pragma unroll 4
    for (int k = 0; k < 128; ++k) hj = fmaf(pooled[k], Wl1[k * 64 + tid], hj);
    const float* xr = xs + g * 4;
    #pragma unroll
    for (int k = 0; k < 4; ++k) hj = fmaf(xr[k], Wl1[(128 + k) * 64 + tid], hj);
    hj = fmaxf(hj, 0.f);
    float val = hj * Wl2[tid];
    #pragma unroll
    for (int off = 32; off > 0; off >>= 1) val += __shfl_down(val, off);
    if (tid == 0) out[g] = val + bl2[0];
  }
}

// ---------------- launcher ----------------

extern "C" void kernel_launch(void* const* d_in, const int* in_sizes, int n_in,
                              void* d_out, int out_size, void* d_ws, size_t ws_size,
                              hipStream_t stream) {
  const float* x    = (const float*)d_in[0];
  const int*   ei   = (const int*)d_in[1];
  const float* xs   = (const float*)d_in[2];
  const int*   batch= (const int*)d_in[3];
  const float* W0   = (const float*)d_in[4];
  const float* b0   = (const float*)d_in[5];
  const float* W1   = (const float*)d_in[6];
  const float* b1   = (const float*)d_in[7];
  const float* W2   = (const float*)d_in[8];
  const float* b2   = (const float*)d_in[9];
  const float* W3   = (const float*)d_in[10];
  const float* b3   = (const float*)d_in[11];
  const float* Wl1  = (const float*)d_in[12];
  const float* bl1  = (const float*)d_in[13];
  const float* Wl2  = (const float*)d_in[14];
  const float* bl2  = (const float*)d_in[15];
  const int* srcA = ei;        // edge_index[0]
  const int* dstA = ei + EE;   // edge_index[1]
  float* out = (float*)d_out;

  char* p = (char*)d_ws;
  auto take = [&](size_t bytes) { char* q = p; p += (bytes + 255) & ~(size_t)255; return q; };
  __bf16* hA    = (__bf16*)take((size_t)NN * 128 * 2);
  __bf16* hB    = (__bf16*)take((size_t)NN * 128 * 2);
  int*    cnt   = (int*)take((size_t)NN * 4);
  int2*   wbucket = (int2*)take((size_t)NN * CAP * 8);
  int*    gstart= (int*)take((size_t)(GG + 1) * 4);
  __bf16* Wt1   = (__bf16*)take(16384 * 2);
  __bf16* Wt2   = (__bf16*)take(16384 * 2);
  __bf16* Wt3   = (__bf16*)take(16384 * 2);

  // setup
  k_init<<<NB, 256, 0, stream>>>(cnt, gstart);
  k_fill<<<(EE + 255) / 256, 256, 0, stream>>>(srcA, dstA, cnt, wbucket);
  k_wb<<<(NN * CAP + 255) / 256, 256, 0, stream>>>(cnt, batch, gstart, W1, W2, W3,
                                                   Wt1, Wt2, Wt3, wbucket);

  // layer 0 fused: h0 = relu(Agg(x)@W0+b0) materialized bf16
  k_l0<<<(NN * 16 + 255) / 256, 256, 0, stream>>>((const float4*)x, cnt, wbucket, W0, b0, (u32*)hA);
  // layers 1-3: g = Agg(h), h' = relu(g@W+b)
  k_agg23<<<(NN + 7) / 8, 256, 0, stream>>>(hA, cnt, wbucket, (u32*)hB);
  k_mfma<<<(NN + 127) / 128, 256, 0, stream>>>(hB, Wt1, b1, hA);
  k_agg23<<<(NN + 7) / 8, 256, 0, stream>>>(hA, cnt, wbucket, (u32*)hB);
  k_mfma<<<(NN + 127) / 128, 256, 0, stream>>>(hB, Wt2, b2, hA);
  k_agg23<<<(NN + 7) / 8, 256, 0, stream>>>(hA, cnt, wbucket, (u32*)hB);
  k_mfma<<<(NN + 127) / 128, 256, 0, stream>>>(hB, Wt3, b3, hA);

  // fused pool + head MLP
  k_poolmlp<<<GG, 256, 0, stream>>>((const uint2*)hA, gstart, xs, Wl1, bl1, Wl2, bl2, out);
}